// Round 7
// baseline (330.467 us; speedup 1.0000x reference)
//
#include <hip/hip_runtime.h>
#include <hip/hip_fp16.h>
#include <math.h>
#include <stdint.h>

#define NEG_SLOPE 0.2f
#define SCAN_TILE 2048

__device__ __forceinline__ float leaky(float a) { return a > 0.f ? a : NEG_SLOPE * a; }

// ---------------- pass 1: degree histogram + within-node position (single atomic pass) ----------------
__global__ __launch_bounds__(256) void k_pw(const int* __restrict__ dst, int* __restrict__ deg,
                                            int* __restrict__ pw, int E) {
    int base = (blockIdx.x * blockDim.x + threadIdx.x) * 4;
    if (base >= E) return;
    if (base + 3 < E) {
        int4 dv = *reinterpret_cast<const int4*>(&dst[base]);
        int4 pv;
        pv.x = atomicAdd(&deg[dv.x], 1);
        pv.y = atomicAdd(&deg[dv.y], 1);
        pv.z = atomicAdd(&deg[dv.z], 1);
        pv.w = atomicAdd(&deg[dv.w], 1);
        *reinterpret_cast<int4*>(&pw[base]) = pv;
    } else {
        for (int i = base; i < E; i++) pw[i] = atomicAdd(&deg[dst[i]], 1);
    }
}

__global__ __launch_bounds__(256) void k_scan_partial(const int* __restrict__ deg, int* __restrict__ tsum, int N) {
    __shared__ int sh[256];
    int b = blockIdx.x, t = threadIdx.x;
    int base = b * SCAN_TILE + t * 8;
    int s = 0;
    #pragma unroll
    for (int i = 0; i < 8; i++) { int idx = base + i; s += (idx < N) ? deg[idx] : 0; }
    sh[t] = s; __syncthreads();
    for (int o = 128; o > 0; o >>= 1) { if (t < o) sh[t] += sh[t + o]; __syncthreads(); }
    if (t == 0) tsum[b] = sh[0];
}

__global__ void k_scan_tsum(const int* __restrict__ tsum, int* __restrict__ toff,
                            int* __restrict__ rowptr, int nb, int N) {
    if (threadIdx.x == 0 && blockIdx.x == 0) {
        int run = 0;
        for (int i = 0; i < nb; i++) { toff[i] = run; run += tsum[i]; }
        rowptr[N] = run;
    }
}

// writes rowptr[] and the rowptr copy inside the packed per-dst record cmb (stride 8 floats)
__global__ __launch_bounds__(256) void k_scan_final(const int* __restrict__ deg, const int* __restrict__ toff,
        int* __restrict__ rowptr, int* __restrict__ cmbi, int N) {
    __shared__ int sh[256];
    int b = blockIdx.x, t = threadIdx.x;
    int base = b * SCAN_TILE + t * 8;
    int v[8]; int s = 0;
    #pragma unroll
    for (int i = 0; i < 8; i++) { int idx = base + i; v[i] = (idx < N) ? deg[idx] : 0; s += v[i]; }
    sh[t] = s; __syncthreads();
    for (int o = 1; o < 256; o <<= 1) {
        int u = (t >= o) ? sh[t - o] : 0;
        __syncthreads();
        sh[t] += u;
        __syncthreads();
    }
    int run = sh[t] - s + toff[b];
    #pragma unroll
    for (int i = 0; i < 8; i++) {
        int idx = base + i;
        if (idx < N) { rowptr[idx] = run; cmbi[(size_t)idx*8 + 4] = run; run += v[i]; }
    }
}

// ---------------- tiny weight precompute ----------------
__global__ void k_prew(const float* __restrict__ We1, const float* __restrict__ ae1,
                       const float* __restrict__ We2, const float* __restrict__ ae2,
                       float* __restrict__ cw) {
    if (threadIdx.x == 0 && blockIdx.x == 0) {
        for (int i = 0; i < 3; i++)
            for (int h = 0; h < 4; h++) {
                float s = 0.f;
                for (int m = 0; m < 16; m++) s += We1[i*64 + h*16 + m] * ae1[h*16 + m];
                cw[i*4 + h] = s;
            }
        for (int i = 0; i < 3; i++) cw[12 + i] = We2[i*2]*ae2[0] + We2[i*2+1]*ae2[1];
    }
}

// ---------------- layer1 node projection: 8 nodes/wave, W1 fragment loaded once per 8 nodes ----------------
__global__ __launch_bounds__(256) void k_proj1(const float* __restrict__ x, const float* __restrict__ W1,
        const float* __restrict__ as1, const float* __restrict__ ad1,
        __half* __restrict__ xs1h, float* __restrict__ as1v, float* __restrict__ cmbf, int N) {
    __shared__ float xr[32][128];                 // 16 KB: 32 node rows
    int tid = threadIdx.x;
    int wave = tid >> 6, lane = tid & 63;
    int nbase = blockIdx.x * 32;
    if (nbase + 32 <= N) {
        const float4* x4 = reinterpret_cast<const float4*>(x + (size_t)nbase * 128);
        #pragma unroll
        for (int i = 0; i < 4; i++) {
            int idx = tid + i * 256;
            reinterpret_cast<float4*>(&xr[0][0])[idx] = x4[idx];
        }
    } else {
        for (int i = 0; i < 16; i++) {
            int flat = tid + i * 256;
            int row = flat >> 7, col = flat & 127;
            int n = nbase + row; if (n >= N) n = N - 1;
            xr[row][col] = x[(size_t)n * 128 + col];
        }
    }
    __syncthreads();
    int cc = lane & 15, kk = lane >> 4;
    int nw = wave * 8;
    const float4* W4 = reinterpret_cast<const float4*>(W1);
    float4 acc[8];
    #pragma unroll
    for (int m = 0; m < 8; m++) acc[m] = make_float4(0.f, 0.f, 0.f, 0.f);
    #pragma unroll 4
    for (int k = kk; k < 128; k += 4) {
        float4 wv = W4[k * 16 + cc];
        #pragma unroll
        for (int m = 0; m < 8; m++) {
            float xv = xr[nw + m][k];
            acc[m].x = fmaf(xv, wv.x, acc[m].x);
            acc[m].y = fmaf(xv, wv.y, acc[m].y);
            acc[m].z = fmaf(xv, wv.z, acc[m].z);
            acc[m].w = fmaf(xv, wv.w, acc[m].w);
        }
    }
    float a_s0 = as1[4*cc], a_s1 = as1[4*cc+1], a_s2 = as1[4*cc+2], a_s3 = as1[4*cc+3];
    float a_d0 = ad1[4*cc], a_d1 = ad1[4*cc+1], a_d2 = ad1[4*cc+2], a_d3 = ad1[4*cc+3];
    #pragma unroll
    for (int m = 0; m < 8; m++) {
        float4 a = acc[m];
        a.x += __shfl_xor(a.x, 16, 64); a.y += __shfl_xor(a.y, 16, 64);
        a.z += __shfl_xor(a.z, 16, 64); a.w += __shfl_xor(a.w, 16, 64);
        a.x += __shfl_xor(a.x, 32, 64); a.y += __shfl_xor(a.y, 32, 64);
        a.z += __shfl_xor(a.z, 32, 64); a.w += __shfl_xor(a.w, 32, 64);
        float ps = a.x*a_s0 + a.y*a_s1 + a.z*a_s2 + a.w*a_s3;
        float pd = a.x*a_d0 + a.y*a_d1 + a.z*a_d2 + a.w*a_d3;
        ps += __shfl_xor(ps, 1, 64); ps += __shfl_xor(ps, 2, 64);
        pd += __shfl_xor(pd, 1, 64); pd += __shfl_xor(pd, 2, 64);
        if (kk == 0) {
            int n = nbase + nw + m; if (n >= N) n = N - 1;
            __half2 h01 = __halves2half2(__float2half_rn(a.x), __float2half_rn(a.y));
            __half2 h23 = __halves2half2(__float2half_rn(a.z), __float2half_rn(a.w));
            uint2 st;
            st.x = *reinterpret_cast<unsigned*>(&h01);
            st.y = *reinterpret_cast<unsigned*>(&h23);
            *reinterpret_cast<uint2*>(&xs1h[(size_t)n*64 + 4*cc]) = st;
            if ((cc & 3) == 0) {
                int h = cc >> 2;
                as1v[n*4 + h] = ps;
                cmbf[(size_t)n*8 + h] = pd;       // ad1v lives in the packed per-dst record
            }
        }
    }
}

// ---------------- edge MLP + weights; payload SEQUENTIAL in edge order; scatter only perm (4B) ----------------
__global__ __launch_bounds__(256) void k_payload(const float* __restrict__ ef,
                       const float* __restrict__ Em1, const float* __restrict__ eb1,
                       const float* __restrict__ Em2, const float* __restrict__ eb2,
                       const float* __restrict__ cw,
                       const int* __restrict__ src, const int* __restrict__ dst,
                       const int* __restrict__ pw,
                       const float4* __restrict__ as1v4,
                       const float* __restrict__ cmbf, const int* __restrict__ cmbi,
                       uint4* __restrict__ pk, int* __restrict__ perm, int E) {
    int base = (blockIdx.x * blockDim.x + threadIdx.x) * 4;
    if (base >= E) return;
    int cnt = min(4, E - base);

    float f[4][3]; int sv[4], dv[4], pv[4];
    if (cnt == 4) {
        const float4* ef4 = reinterpret_cast<const float4*>(ef);
        float4 a = ef4[base*3/4 + 0], b = ef4[base*3/4 + 1], c = ef4[base*3/4 + 2];
        f[0][0]=a.x; f[0][1]=a.y; f[0][2]=a.z;
        f[1][0]=a.w; f[1][1]=b.x; f[1][2]=b.y;
        f[2][0]=b.z; f[2][1]=b.w; f[2][2]=c.x;
        f[3][0]=c.y; f[3][1]=c.z; f[3][2]=c.w;
        int4 s4 = *reinterpret_cast<const int4*>(&src[base]);
        int4 d4 = *reinterpret_cast<const int4*>(&dst[base]);
        int4 p4 = *reinterpret_cast<const int4*>(&pw[base]);
        sv[0]=s4.x; sv[1]=s4.y; sv[2]=s4.z; sv[3]=s4.w;
        dv[0]=d4.x; dv[1]=d4.y; dv[2]=d4.z; dv[3]=d4.w;
        pv[0]=p4.x; pv[1]=p4.y; pv[2]=p4.z; pv[3]=p4.w;
    } else {
        for (int i = 0; i < cnt; i++) {
            f[i][0]=ef[(base+i)*3+0]; f[i][1]=ef[(base+i)*3+1]; f[i][2]=ef[(base+i)*3+2];
            sv[i]=src[base+i]; dv[i]=dst[base+i]; pv[i]=pw[base+i];
        }
    }

    #pragma unroll
    for (int i = 0; i < 4; i++) {
        if (i >= cnt) break;
        float f0=f[i][0], f1=f[i][1], f2=f[i][2];
        float t0 = fmaxf(f0*Em1[0]+f1*Em1[3]+f2*Em1[6]+eb1[0], 0.f);
        float t1 = fmaxf(f0*Em1[1]+f1*Em1[4]+f2*Em1[7]+eb1[1], 0.f);
        float t2 = fmaxf(f0*Em1[2]+f1*Em1[5]+f2*Em1[8]+eb1[2], 0.f);
        float u0 = t0*Em2[0]+t1*Em2[3]+t2*Em2[6]+eb2[0];
        float u1 = t0*Em2[1]+t1*Em2[4]+t2*Em2[7]+eb2[1];
        float u2 = t0*Em2[2]+t1*Em2[5]+t2*Em2[8]+eb2[2];
        int s = sv[i], d = dv[i];
        float4 av = as1v4[s];
        float4 bv = *reinterpret_cast<const float4*>(&cmbf[(size_t)d*8]);   // ad1v
        int rp = cmbi[(size_t)d*8 + 4];                                      // rowptr[d], same line
        float w0 = __expf(leaky(av.x + bv.x + u0*cw[0] + u1*cw[4] + u2*cw[8]));
        float w1 = __expf(leaky(av.y + bv.y + u0*cw[1] + u1*cw[5] + u2*cw[9]));
        float w2 = __expf(leaky(av.z + bv.z + u0*cw[2] + u1*cw[6] + u2*cw[10]));
        float w3 = __expf(leaky(av.w + bv.w + u0*cw[3] + u1*cw[7] + u2*cw[11]));
        float e2 = u0*cw[12] + u1*cw[13] + u2*cw[14];
        __half2 lo = __halves2half2(__float2half_rn(w0), __float2half_rn(w1));
        __half2 hi = __halves2half2(__float2half_rn(w2), __float2half_rn(w3));
        uint4 pki;
        pki.x = (unsigned)s;
        pki.y = *reinterpret_cast<unsigned*>(&lo);
        pki.z = *reinterpret_cast<unsigned*>(&hi);
        pki.w = *reinterpret_cast<unsigned*>(&e2);
        pk[base + i] = pki;               // SEQUENTIAL coalesced 16B store
        perm[rp + pv[i]] = base + i;      // 4B scatter into L2-sized array
    }
}

// ---------------- fused layer1: aggregate + ELU + proj2 epilogue ----------------
__global__ __launch_bounds__(256) void k_gat1(
        const int* __restrict__ rowptr, const int* __restrict__ perm,
        const uint4* __restrict__ pk, const __half* __restrict__ xs1h,
        const float* __restrict__ b1, const float* __restrict__ W2,
        const float* __restrict__ as2, const float* __restrict__ ad2,
        float2* __restrict__ pk2, float* __restrict__ ad2v, int N) {
    int wave = threadIdx.x >> 6, lane = threadIdx.x & 63;
    int d = blockIdx.x * 4 + wave;
    if (d >= N) return;
    int beg = rowptr[d], end = rowptr[d+1];
    int jj = lane >> 2, hh = lane & 3;
    int k = lane, hk = lane >> 4;
    float smacc = 0.f, acc = 0.f;
    for (int off = beg; off < end; off += 16) {
        int j = off + jj;
        float w = 0.f; int s = 0;
        if (j < end) {
            uint4 p = pk[perm[j]];
            s = (int)p.x;
            unsigned wb = (hh < 2) ? p.y : p.z;
            __half2 h2 = *reinterpret_cast<__half2*>(&wb);
            w = (hh & 1) ? __high2float(h2) : __low2float(h2);
        }
        smacc += w;
        if (end - off >= 16) {
            #pragma unroll
            for (int t = 0; t < 16; ++t) {
                float wt = __shfl(w, t*4 + hk, 64);
                int st   = __shfl(s, t*4, 64);
                acc = fmaf(wt, __half2float(xs1h[(size_t)st*64 + k]), acc);
            }
        } else {
            int lim = end - off;
            for (int t = 0; t < lim; ++t) {
                float wt = __shfl(w, t*4 + hk, 64);
                int st   = __shfl(s, t*4, 64);
                acc = fmaf(wt, __half2float(xs1h[(size_t)st*64 + k]), acc);
            }
        }
    }
    smacc += __shfl_xor(smacc, 4, 64);
    smacc += __shfl_xor(smacc, 8, 64);
    smacc += __shfl_xor(smacc, 16, 64);
    smacc += __shfl_xor(smacc, 32, 64);
    float sm = __shfl(smacc, hk, 64);
    float h = acc / (sm + 1e-16f);
    float v = h + b1[k];
    v = v > 0.f ? v : expm1f(v);
    float p0 = v * W2[k*2 + 0], p1 = v * W2[k*2 + 1];
    #pragma unroll
    for (int o = 32; o >= 1; o >>= 1) { p0 += __shfl_xor(p0,o,64); p1 += __shfl_xor(p1,o,64); }
    if (lane == 0) {
        float2 q;
        q.x = p0*as2[0] + p1*as2[1];
        __half2 xv = __halves2half2(__float2half_rn(p0), __float2half_rn(p1));
        q.y = *reinterpret_cast<float*>(&xv);
        pk2[d] = q;
        ad2v[d] = p0*ad2[0] + p1*ad2[1];
    }
}

// ---------------- fused layer2: single pass, 16 lanes per node ----------------
__global__ __launch_bounds__(256) void k_gat2(
        const int* __restrict__ rowptr, const int* __restrict__ perm,
        const uint4* __restrict__ pk,
        const float2* __restrict__ pk2, const float* __restrict__ ad2v,
        const float* __restrict__ b2, float* __restrict__ out, int N) {
    int t = blockIdx.x * blockDim.x + threadIdx.x;
    int d = t >> 4, j16 = t & 15;
    if (d >= N) return;
    int beg = rowptr[d], end = rowptr[d+1];
    float add = ad2v[d];
    float sm = 0.f, p0 = 0.f, p1 = 0.f;
    for (int off = beg; off < end; off += 16) {
        int j = off + j16;
        if (j < end) {
            uint4 p = pk[perm[j]];
            int s = (int)p.x;
            float ea2 = *reinterpret_cast<float*>(&p.w);
            float2 q = pk2[s];
            float w = __expf(leaky(q.x + add + ea2));
            __half2 xv = *reinterpret_cast<__half2*>(&q.y);
            p0 = fmaf(w, __low2float(xv), p0);
            p1 = fmaf(w, __high2float(xv), p1);
            sm += w;
        }
    }
    #pragma unroll
    for (int o = 1; o < 16; o <<= 1) {
        sm += __shfl_xor(sm, o, 16);
        p0 += __shfl_xor(p0, o, 16);
        p1 += __shfl_xor(p1, o, 16);
    }
    if (j16 == 0) {
        float inv = 1.f / (sm + 1e-16f);
        out[d*2+0] = p0*inv + b2[0];
        out[d*2+1] = p1*inv + b2[1];
    }
}

extern "C" void kernel_launch(void* const* d_in, const int* in_sizes, int n_in,
                              void* d_out, int out_size, void* d_ws, size_t ws_size,
                              hipStream_t stream) {
    const float* x   = (const float*)d_in[0];
    const int*   ei  = (const int*)d_in[1];
    const float* ef  = (const float*)d_in[2];
    const float* Em1 = (const float*)d_in[3];
    const float* eb1 = (const float*)d_in[4];
    const float* Em2 = (const float*)d_in[5];
    const float* eb2 = (const float*)d_in[6];
    const float* W1  = (const float*)d_in[7];
    const float* as1 = (const float*)d_in[8];
    const float* ad1 = (const float*)d_in[9];
    const float* We1 = (const float*)d_in[10];
    const float* ae1 = (const float*)d_in[11];
    const float* b1  = (const float*)d_in[12];
    const float* W2  = (const float*)d_in[13];
    const float* as2 = (const float*)d_in[14];
    const float* ad2 = (const float*)d_in[15];
    const float* We2 = (const float*)d_in[16];
    const float* ae2 = (const float*)d_in[17];
    const float* b2  = (const float*)d_in[18];

    const int N = in_sizes[0] / 128;
    const int E = in_sizes[1] / 2;
    const int* srcp = ei;
    const int* dstp = ei + E;

    uintptr_t w = (uintptr_t)d_ws;
    auto alloc = [&](size_t bytes) -> void* {
        uintptr_t p = w; w += (bytes + 255) & ~(size_t)255; return (void*)p;
    };
    const int nb = (N + SCAN_TILE - 1) / SCAN_TILE;
    int*    deg     = (int*)alloc((size_t)N * sizeof(int));
    int*    rowptr  = (int*)alloc(((size_t)N + 1) * sizeof(int));
    int*    tsum    = (int*)alloc((size_t)nb * sizeof(int));
    int*    toff    = (int*)alloc((size_t)(nb + 1) * sizeof(int));
    float*  cw      = (float*)alloc(16 * sizeof(float));
    int*    pw      = (int*)alloc((size_t)E * sizeof(int));
    int*    perm    = (int*)alloc((size_t)E * sizeof(int));
    uint4*  pk      = (uint4*)alloc((size_t)E * sizeof(uint4));
    __half* xs1h    = (__half*)alloc((size_t)N * 64 * sizeof(__half));
    float*  as1v    = (float*)alloc((size_t)N * 4 * sizeof(float));
    float*  cmb     = (float*)alloc((size_t)N * 8 * sizeof(float));   // {ad1v float4, rowptr int, pad}
    float2* pk2     = (float2*)alloc((size_t)N * sizeof(float2));
    float*  ad2v    = (float*)alloc((size_t)N * sizeof(float));

    const int B = 256;

    hipMemsetAsync(deg, 0, (size_t)N * sizeof(int), stream);
    k_pw<<<(E/4+B-1)/B + 1, B, 0, stream>>>(dstp, deg, pw, E);
    k_scan_partial<<<nb, 256, 0, stream>>>(deg, tsum, N);
    k_scan_tsum<<<1, 64, 0, stream>>>(tsum, toff, rowptr, nb, N);
    k_scan_final<<<nb, 256, 0, stream>>>(deg, toff, rowptr, (int*)cmb, N);
    k_prew<<<1, 64, 0, stream>>>(We1, ae1, We2, ae2, cw);
    k_proj1<<<(N+31)/32, 256, 0, stream>>>(x, W1, as1, ad1, xs1h, as1v, cmb, N);
    k_payload<<<(E/4+B-1)/B + 1, B, 0, stream>>>(ef, Em1, eb1, Em2, eb2, cw,
                                                 srcp, dstp, pw, (const float4*)as1v,
                                                 cmb, (const int*)cmb, pk, perm, E);
    k_gat1<<<(N+3)/4, 256, 0, stream>>>(rowptr, perm, pk, xs1h, b1, W2, as2, ad2, pk2, ad2v, N);
    k_gat2<<<(N*16+B-1)/B, B, 0, stream>>>(rowptr, perm, pk, pk2, ad2v, b2, (float*)d_out, N);
}

// Round 8
// 276.020 us; speedup vs baseline: 1.1973x; 1.1973x over previous
//
#include <hip/hip_runtime.h>
#include <hip/hip_fp16.h>
#include <math.h>
#include <stdint.h>

#define NEG_SLOPE 0.2f
#define SCAN_TILE 2048

__device__ __forceinline__ float leaky(float a) { return a > 0.f ? a : NEG_SLOPE * a; }

// ---------------- pass 1: degree histogram + within-node position (single atomic pass) ----------------
// thread 0 of block 0 also precomputes cw[0..11] (We1·ae1 per head) and cw[12..14] (layer2).
__global__ __launch_bounds__(256) void k_pw(const int* __restrict__ dst, int* __restrict__ deg,
                                            int* __restrict__ pw, int E,
                                            const float* __restrict__ We1, const float* __restrict__ ae1,
                                            const float* __restrict__ We2, const float* __restrict__ ae2,
                                            float* __restrict__ cw) {
    if (blockIdx.x == 0 && threadIdx.x == 0) {
        for (int i = 0; i < 3; i++)
            for (int h = 0; h < 4; h++) {
                float s = 0.f;
                for (int m = 0; m < 16; m++) s += We1[i*64 + h*16 + m] * ae1[h*16 + m];
                cw[i*4 + h] = s;
            }
        for (int i = 0; i < 3; i++) cw[12 + i] = We2[i*2]*ae2[0] + We2[i*2+1]*ae2[1];
    }
    int base = (blockIdx.x * blockDim.x + threadIdx.x) * 4;
    if (base >= E) return;
    if (base + 3 < E) {
        int4 dv = *reinterpret_cast<const int4*>(&dst[base]);
        int4 pv;
        pv.x = atomicAdd(&deg[dv.x], 1);
        pv.y = atomicAdd(&deg[dv.y], 1);
        pv.z = atomicAdd(&deg[dv.z], 1);
        pv.w = atomicAdd(&deg[dv.w], 1);
        *reinterpret_cast<int4*>(&pw[base]) = pv;
    } else {
        for (int i = base; i < E; i++) pw[i] = atomicAdd(&deg[dst[i]], 1);
    }
}

__global__ __launch_bounds__(256) void k_scan_partial(const int* __restrict__ deg, int* __restrict__ tsum, int N) {
    __shared__ int sh[256];
    int b = blockIdx.x, t = threadIdx.x;
    int base = b * SCAN_TILE + t * 8;
    int s = 0;
    #pragma unroll
    for (int i = 0; i < 8; i++) { int idx = base + i; s += (idx < N) ? deg[idx] : 0; }
    sh[t] = s; __syncthreads();
    for (int o = 128; o > 0; o >>= 1) { if (t < o) sh[t] += sh[t + o]; __syncthreads(); }
    if (t == 0) tsum[b] = sh[0];
}

__global__ void k_scan_tsum(const int* __restrict__ tsum, int* __restrict__ toff,
                            int* __restrict__ rowptr, int nb, int N) {
    if (threadIdx.x == 0 && blockIdx.x == 0) {
        int run = 0;
        for (int i = 0; i < nb; i++) { toff[i] = run; run += tsum[i]; }
        rowptr[N] = run;
    }
}

// writes rowptr[] and the rowptr copy inside the packed per-dst record cmb (stride 8 words)
__global__ __launch_bounds__(256) void k_scan_final(const int* __restrict__ deg, const int* __restrict__ toff,
        int* __restrict__ rowptr, int* __restrict__ cmbi, int N) {
    __shared__ int sh[256];
    int b = blockIdx.x, t = threadIdx.x;
    int base = b * SCAN_TILE + t * 8;
    int v[8]; int s = 0;
    #pragma unroll
    for (int i = 0; i < 8; i++) { int idx = base + i; v[i] = (idx < N) ? deg[idx] : 0; s += v[i]; }
    sh[t] = s; __syncthreads();
    for (int o = 1; o < 256; o <<= 1) {
        int u = (t >= o) ? sh[t - o] : 0;
        __syncthreads();
        sh[t] += u;
        __syncthreads();
    }
    int run = sh[t] - s + toff[b];
    #pragma unroll
    for (int i = 0; i < 8; i++) {
        int idx = base + i;
        if (idx < N) { rowptr[idx] = run; cmbi[(size_t)idx*8 + 4] = run; run += v[i]; }
    }
}

// ---------------- layer1 node projection: 8 nodes/wave, W1 fragment loaded once per 8 nodes ----------------
__global__ __launch_bounds__(256) void k_proj1(const float* __restrict__ x, const float* __restrict__ W1,
        const float* __restrict__ as1, const float* __restrict__ ad1,
        __half* __restrict__ xs1h, float* __restrict__ as1v, float* __restrict__ cmbf, int N) {
    __shared__ float xr[32][128];                 // 16 KB: 32 node rows
    int tid = threadIdx.x;
    int wave = tid >> 6, lane = tid & 63;
    int nbase = blockIdx.x * 32;
    if (nbase + 32 <= N) {
        const float4* x4 = reinterpret_cast<const float4*>(x + (size_t)nbase * 128);
        #pragma unroll
        for (int i = 0; i < 4; i++) {
            int idx = tid + i * 256;
            reinterpret_cast<float4*>(&xr[0][0])[idx] = x4[idx];
        }
    } else {
        for (int i = 0; i < 16; i++) {
            int flat = tid + i * 256;
            int row = flat >> 7, col = flat & 127;
            int n = nbase + row; if (n >= N) n = N - 1;
            xr[row][col] = x[(size_t)n * 128 + col];
        }
    }
    __syncthreads();
    int cc = lane & 15, kk = lane >> 4;
    int nw = wave * 8;
    const float4* W4 = reinterpret_cast<const float4*>(W1);
    float4 acc[8];
    #pragma unroll
    for (int m = 0; m < 8; m++) acc[m] = make_float4(0.f, 0.f, 0.f, 0.f);
    #pragma unroll 4
    for (int k = kk; k < 128; k += 4) {
        float4 wv = W4[k * 16 + cc];
        #pragma unroll
        for (int m = 0; m < 8; m++) {
            float xv = xr[nw + m][k];
            acc[m].x = fmaf(xv, wv.x, acc[m].x);
            acc[m].y = fmaf(xv, wv.y, acc[m].y);
            acc[m].z = fmaf(xv, wv.z, acc[m].z);
            acc[m].w = fmaf(xv, wv.w, acc[m].w);
        }
    }
    float a_s0 = as1[4*cc], a_s1 = as1[4*cc+1], a_s2 = as1[4*cc+2], a_s3 = as1[4*cc+3];
    float a_d0 = ad1[4*cc], a_d1 = ad1[4*cc+1], a_d2 = ad1[4*cc+2], a_d3 = ad1[4*cc+3];
    #pragma unroll
    for (int m = 0; m < 8; m++) {
        float4 a = acc[m];
        a.x += __shfl_xor(a.x, 16, 64); a.y += __shfl_xor(a.y, 16, 64);
        a.z += __shfl_xor(a.z, 16, 64); a.w += __shfl_xor(a.w, 16, 64);
        a.x += __shfl_xor(a.x, 32, 64); a.y += __shfl_xor(a.y, 32, 64);
        a.z += __shfl_xor(a.z, 32, 64); a.w += __shfl_xor(a.w, 32, 64);
        float ps = a.x*a_s0 + a.y*a_s1 + a.z*a_s2 + a.w*a_s3;
        float pd = a.x*a_d0 + a.y*a_d1 + a.z*a_d2 + a.w*a_d3;
        ps += __shfl_xor(ps, 1, 64); ps += __shfl_xor(ps, 2, 64);
        pd += __shfl_xor(pd, 1, 64); pd += __shfl_xor(pd, 2, 64);
        if (kk == 0) {
            int n = nbase + nw + m; if (n >= N) n = N - 1;
            __half2 h01 = __halves2half2(__float2half_rn(a.x), __float2half_rn(a.y));
            __half2 h23 = __halves2half2(__float2half_rn(a.z), __float2half_rn(a.w));
            uint2 st;
            st.x = *reinterpret_cast<unsigned*>(&h01);
            st.y = *reinterpret_cast<unsigned*>(&h23);
            *reinterpret_cast<uint2*>(&xs1h[(size_t)n*64 + 4*cc]) = st;
            if ((cc & 3) == 0) {
                int h = cc >> 2;
                as1v[n*4 + h] = ps;
                cmbf[(size_t)n*8 + h] = pd;       // ad1v lives in the packed per-dst record
            }
        }
    }
}

// ---------------- edge MLP + weights; direct 16B scatter to CSR slot (no atomics here) ----------------
__global__ __launch_bounds__(256) void k_payload(const float* __restrict__ ef,
                       const float* __restrict__ Em1, const float* __restrict__ eb1,
                       const float* __restrict__ Em2, const float* __restrict__ eb2,
                       const float* __restrict__ cw,
                       const int* __restrict__ src, const int* __restrict__ dst,
                       const int* __restrict__ pw,
                       const float4* __restrict__ as1v4,
                       const float* __restrict__ cmbf, const int* __restrict__ cmbi,
                       uint4* __restrict__ csr_pk, int E) {
    int base = (blockIdx.x * blockDim.x + threadIdx.x) * 4;
    if (base >= E) return;
    int cnt = min(4, E - base);

    float f[4][3]; int sv[4], dv[4], pv[4];
    if (cnt == 4) {
        const float4* ef4 = reinterpret_cast<const float4*>(ef);
        float4 a = ef4[base*3/4 + 0], b = ef4[base*3/4 + 1], c = ef4[base*3/4 + 2];
        f[0][0]=a.x; f[0][1]=a.y; f[0][2]=a.z;
        f[1][0]=a.w; f[1][1]=b.x; f[1][2]=b.y;
        f[2][0]=b.z; f[2][1]=b.w; f[2][2]=c.x;
        f[3][0]=c.y; f[3][1]=c.z; f[3][2]=c.w;
        int4 s4 = *reinterpret_cast<const int4*>(&src[base]);
        int4 d4 = *reinterpret_cast<const int4*>(&dst[base]);
        int4 p4 = *reinterpret_cast<const int4*>(&pw[base]);
        sv[0]=s4.x; sv[1]=s4.y; sv[2]=s4.z; sv[3]=s4.w;
        dv[0]=d4.x; dv[1]=d4.y; dv[2]=d4.z; dv[3]=d4.w;
        pv[0]=p4.x; pv[1]=p4.y; pv[2]=p4.z; pv[3]=p4.w;
    } else {
        for (int i = 0; i < cnt; i++) {
            f[i][0]=ef[(base+i)*3+0]; f[i][1]=ef[(base+i)*3+1]; f[i][2]=ef[(base+i)*3+2];
            sv[i]=src[base+i]; dv[i]=dst[base+i]; pv[i]=pw[base+i];
        }
    }

    #pragma unroll
    for (int i = 0; i < 4; i++) {
        if (i >= cnt) break;
        float f0=f[i][0], f1=f[i][1], f2=f[i][2];
        float t0 = fmaxf(f0*Em1[0]+f1*Em1[3]+f2*Em1[6]+eb1[0], 0.f);
        float t1 = fmaxf(f0*Em1[1]+f1*Em1[4]+f2*Em1[7]+eb1[1], 0.f);
        float t2 = fmaxf(f0*Em1[2]+f1*Em1[5]+f2*Em1[8]+eb1[2], 0.f);
        float u0 = t0*Em2[0]+t1*Em2[3]+t2*Em2[6]+eb2[0];
        float u1 = t0*Em2[1]+t1*Em2[4]+t2*Em2[7]+eb2[1];
        float u2 = t0*Em2[2]+t1*Em2[5]+t2*Em2[8]+eb2[2];
        int s = sv[i], d = dv[i];
        float4 av = as1v4[s];
        float4 bv = *reinterpret_cast<const float4*>(&cmbf[(size_t)d*8]);   // ad1v
        int rp = cmbi[(size_t)d*8 + 4];                                      // rowptr[d], same line
        float w0 = __expf(leaky(av.x + bv.x + u0*cw[0] + u1*cw[4] + u2*cw[8]));
        float w1 = __expf(leaky(av.y + bv.y + u0*cw[1] + u1*cw[5] + u2*cw[9]));
        float w2 = __expf(leaky(av.z + bv.z + u0*cw[2] + u1*cw[6] + u2*cw[10]));
        float w3 = __expf(leaky(av.w + bv.w + u0*cw[3] + u1*cw[7] + u2*cw[11]));
        float e2 = u0*cw[12] + u1*cw[13] + u2*cw[14];
        __half2 lo = __halves2half2(__float2half_rn(w0), __float2half_rn(w1));
        __half2 hi = __halves2half2(__float2half_rn(w2), __float2half_rn(w3));
        uint4 pki;
        pki.x = (unsigned)s;
        pki.y = *reinterpret_cast<unsigned*>(&lo);
        pki.z = *reinterpret_cast<unsigned*>(&hi);
        pki.w = *reinterpret_cast<unsigned*>(&e2);
        csr_pk[rp + pv[i]] = pki;         // position known; fire-and-forget 16B scatter
    }
}

// ---------------- fused layer1: aggregate + ELU + proj2 epilogue (sequential payload reads) ----------------
__global__ __launch_bounds__(256) void k_gat1(
        const int* __restrict__ rowptr, const uint4* __restrict__ csr_pk,
        const __half* __restrict__ xs1h,
        const float* __restrict__ b1, const float* __restrict__ W2,
        const float* __restrict__ as2, const float* __restrict__ ad2,
        float2* __restrict__ pk2, float* __restrict__ ad2v, int N) {
    int wave = threadIdx.x >> 6, lane = threadIdx.x & 63;
    int d = blockIdx.x * 4 + wave;
    if (d >= N) return;
    int beg = rowptr[d], end = rowptr[d+1];
    int jj = lane >> 2, hh = lane & 3;
    int k = lane, hk = lane >> 4;
    float smacc = 0.f, acc = 0.f;
    for (int off = beg; off < end; off += 16) {
        int j = off + jj;
        float w = 0.f; int s = 0;
        if (j < end) {
            uint4 p = csr_pk[j];
            s = (int)p.x;
            unsigned wb = (hh < 2) ? p.y : p.z;
            __half2 h2 = *reinterpret_cast<__half2*>(&wb);
            w = (hh & 1) ? __high2float(h2) : __low2float(h2);
        }
        smacc += w;
        if (end - off >= 16) {
            #pragma unroll
            for (int t = 0; t < 16; ++t) {
                float wt = __shfl(w, t*4 + hk, 64);
                int st   = __shfl(s, t*4, 64);
                acc = fmaf(wt, __half2float(xs1h[(size_t)st*64 + k]), acc);
            }
        } else {
            int lim = end - off;
            for (int t = 0; t < lim; ++t) {
                float wt = __shfl(w, t*4 + hk, 64);
                int st   = __shfl(s, t*4, 64);
                acc = fmaf(wt, __half2float(xs1h[(size_t)st*64 + k]), acc);
            }
        }
    }
    smacc += __shfl_xor(smacc, 4, 64);
    smacc += __shfl_xor(smacc, 8, 64);
    smacc += __shfl_xor(smacc, 16, 64);
    smacc += __shfl_xor(smacc, 32, 64);
    float sm = __shfl(smacc, hk, 64);
    float h = acc / (sm + 1e-16f);
    float v = h + b1[k];
    v = v > 0.f ? v : expm1f(v);
    float p0 = v * W2[k*2 + 0], p1 = v * W2[k*2 + 1];
    #pragma unroll
    for (int o = 32; o >= 1; o >>= 1) { p0 += __shfl_xor(p0,o,64); p1 += __shfl_xor(p1,o,64); }
    if (lane == 0) {
        float2 q;
        q.x = p0*as2[0] + p1*as2[1];
        __half2 xv = __halves2half2(__float2half_rn(p0), __float2half_rn(p1));
        q.y = *reinterpret_cast<float*>(&xv);
        pk2[d] = q;
        ad2v[d] = p0*ad2[0] + p1*ad2[1];
    }
}

// ---------------- fused layer2: single pass, 16 lanes per node (sequential payload reads) ----------------
__global__ __launch_bounds__(256) void k_gat2(
        const int* __restrict__ rowptr, const uint4* __restrict__ csr_pk,
        const float2* __restrict__ pk2, const float* __restrict__ ad2v,
        const float* __restrict__ b2, float* __restrict__ out, int N) {
    int t = blockIdx.x * blockDim.x + threadIdx.x;
    int d = t >> 4, j16 = t & 15;
    if (d >= N) return;
    int beg = rowptr[d], end = rowptr[d+1];
    float add = ad2v[d];
    float sm = 0.f, p0 = 0.f, p1 = 0.f;
    for (int off = beg; off < end; off += 16) {
        int j = off + j16;
        if (j < end) {
            uint4 p = csr_pk[j];
            int s = (int)p.x;
            float ea2 = *reinterpret_cast<float*>(&p.w);
            float2 q = pk2[s];
            float w = __expf(leaky(q.x + add + ea2));
            __half2 xv = *reinterpret_cast<__half2*>(&q.y);
            p0 = fmaf(w, __low2float(xv), p0);
            p1 = fmaf(w, __high2float(xv), p1);
            sm += w;
        }
    }
    #pragma unroll
    for (int o = 1; o < 16; o <<= 1) {
        sm += __shfl_xor(sm, o, 16);
        p0 += __shfl_xor(p0, o, 16);
        p1 += __shfl_xor(p1, o, 16);
    }
    if (j16 == 0) {
        float inv = 1.f / (sm + 1e-16f);
        out[d*2+0] = p0*inv + b2[0];
        out[d*2+1] = p1*inv + b2[1];
    }
}

extern "C" void kernel_launch(void* const* d_in, const int* in_sizes, int n_in,
                              void* d_out, int out_size, void* d_ws, size_t ws_size,
                              hipStream_t stream) {
    const float* x   = (const float*)d_in[0];
    const int*   ei  = (const int*)d_in[1];
    const float* ef  = (const float*)d_in[2];
    const float* Em1 = (const float*)d_in[3];
    const float* eb1 = (const float*)d_in[4];
    const float* Em2 = (const float*)d_in[5];
    const float* eb2 = (const float*)d_in[6];
    const float* W1  = (const float*)d_in[7];
    const float* as1 = (const float*)d_in[8];
    const float* ad1 = (const float*)d_in[9];
    const float* We1 = (const float*)d_in[10];
    const float* ae1 = (const float*)d_in[11];
    const float* b1  = (const float*)d_in[12];
    const float* W2  = (const float*)d_in[13];
    const float* as2 = (const float*)d_in[14];
    const float* ad2 = (const float*)d_in[15];
    const float* We2 = (const float*)d_in[16];
    const float* ae2 = (const float*)d_in[17];
    const float* b2  = (const float*)d_in[18];

    const int N = in_sizes[0] / 128;
    const int E = in_sizes[1] / 2;
    const int* srcp = ei;
    const int* dstp = ei + E;

    uintptr_t w = (uintptr_t)d_ws;
    auto alloc = [&](size_t bytes) -> void* {
        uintptr_t p = w; w += (bytes + 255) & ~(size_t)255; return (void*)p;
    };
    const int nb = (N + SCAN_TILE - 1) / SCAN_TILE;
    int*    deg     = (int*)alloc((size_t)N * sizeof(int));
    int*    rowptr  = (int*)alloc(((size_t)N + 1) * sizeof(int));
    int*    tsum    = (int*)alloc((size_t)nb * sizeof(int));
    int*    toff    = (int*)alloc((size_t)(nb + 1) * sizeof(int));
    float*  cw      = (float*)alloc(16 * sizeof(float));
    int*    pw      = (int*)alloc((size_t)E * sizeof(int));
    uint4*  csr_pk  = (uint4*)alloc((size_t)E * sizeof(uint4));
    __half* xs1h    = (__half*)alloc((size_t)N * 64 * sizeof(__half));
    float*  as1v    = (float*)alloc((size_t)N * 4 * sizeof(float));
    float*  cmb     = (float*)alloc((size_t)N * 8 * sizeof(float));   // {ad1v float4, rowptr int, pad}
    float2* pk2     = (float2*)alloc((size_t)N * sizeof(float2));
    float*  ad2v    = (float*)alloc((size_t)N * sizeof(float));

    const int B = 256;

    hipMemsetAsync(deg, 0, (size_t)N * sizeof(int), stream);
    k_pw<<<(E/4+B-1)/B + 1, B, 0, stream>>>(dstp, deg, pw, E, We1, ae1, We2, ae2, cw);
    k_scan_partial<<<nb, 256, 0, stream>>>(deg, tsum, N);
    k_scan_tsum<<<1, 64, 0, stream>>>(tsum, toff, rowptr, nb, N);
    k_scan_final<<<nb, 256, 0, stream>>>(deg, toff, rowptr, (int*)cmb, N);
    k_proj1<<<(N+31)/32, 256, 0, stream>>>(x, W1, as1, ad1, xs1h, as1v, cmb, N);
    k_payload<<<(E/4+B-1)/B + 1, B, 0, stream>>>(ef, Em1, eb1, Em2, eb2, cw,
                                                 srcp, dstp, pw, (const float4*)as1v,
                                                 cmb, (const int*)cmb, csr_pk, E);
    k_gat1<<<(N+3)/4, 256, 0, stream>>>(rowptr, csr_pk, xs1h, b1, W2, as2, ad2, pk2, ad2v, N);
    k_gat2<<<(N*16+B-1)/B, B, 0, stream>>>(rowptr, csr_pk, pk2, ad2v, b2, (float*)d_out, N);
}

// Round 9
// 274.592 us; speedup vs baseline: 1.2035x; 1.0052x over previous
//
#include <hip/hip_runtime.h>
#include <hip/hip_fp16.h>
#include <math.h>
#include <stdint.h>

#define NEG_SLOPE 0.2f
#define SCAN_TILE 2048

__device__ __forceinline__ float leaky(float a) { return a > 0.f ? a : NEG_SLOPE * a; }

// ---------------- pass 1: degree histogram + within-node position (single atomic pass) ----------------
// thread 0 of block 0 also precomputes cw[0..11] (We1·ae1 per head) and cw[12..14] (layer2).
__global__ __launch_bounds__(256) void k_pw(const int* __restrict__ dst, int* __restrict__ deg,
                                            int* __restrict__ pw, int E,
                                            const float* __restrict__ We1, const float* __restrict__ ae1,
                                            const float* __restrict__ We2, const float* __restrict__ ae2,
                                            float* __restrict__ cw) {
    if (blockIdx.x == 0 && threadIdx.x == 0) {
        for (int i = 0; i < 3; i++)
            for (int h = 0; h < 4; h++) {
                float s = 0.f;
                for (int m = 0; m < 16; m++) s += We1[i*64 + h*16 + m] * ae1[h*16 + m];
                cw[i*4 + h] = s;
            }
        for (int i = 0; i < 3; i++) cw[12 + i] = We2[i*2]*ae2[0] + We2[i*2+1]*ae2[1];
    }
    int base = (blockIdx.x * blockDim.x + threadIdx.x) * 4;
    if (base >= E) return;
    if (base + 3 < E) {
        int4 dv = *reinterpret_cast<const int4*>(&dst[base]);
        int4 pv;
        pv.x = atomicAdd(&deg[dv.x], 1);
        pv.y = atomicAdd(&deg[dv.y], 1);
        pv.z = atomicAdd(&deg[dv.z], 1);
        pv.w = atomicAdd(&deg[dv.w], 1);
        *reinterpret_cast<int4*>(&pw[base]) = pv;
    } else {
        for (int i = base; i < E; i++) pw[i] = atomicAdd(&deg[dst[i]], 1);
    }
}

__global__ __launch_bounds__(256) void k_scan_partial(const int* __restrict__ deg, int* __restrict__ tsum, int N) {
    __shared__ int sh[256];
    int b = blockIdx.x, t = threadIdx.x;
    int base = b * SCAN_TILE + t * 8;
    int s = 0;
    #pragma unroll
    for (int i = 0; i < 8; i++) { int idx = base + i; s += (idx < N) ? deg[idx] : 0; }
    sh[t] = s; __syncthreads();
    for (int o = 128; o > 0; o >>= 1) { if (t < o) sh[t] += sh[t + o]; __syncthreads(); }
    if (t == 0) tsum[b] = sh[0];
}

__global__ void k_scan_tsum(const int* __restrict__ tsum, int* __restrict__ toff,
                            int* __restrict__ rowptr, int nb, int N) {
    if (threadIdx.x == 0 && blockIdx.x == 0) {
        int run = 0;
        for (int i = 0; i < nb; i++) { toff[i] = run; run += tsum[i]; }
        rowptr[N] = run;
    }
}

// writes rowptr[] and the rowptr copy inside the packed per-dst record cmb (stride 8 words)
__global__ __launch_bounds__(256) void k_scan_final(const int* __restrict__ deg, const int* __restrict__ toff,
        int* __restrict__ rowptr, int* __restrict__ cmbi, int N) {
    __shared__ int sh[256];
    int b = blockIdx.x, t = threadIdx.x;
    int base = b * SCAN_TILE + t * 8;
    int v[8]; int s = 0;
    #pragma unroll
    for (int i = 0; i < 8; i++) { int idx = base + i; v[i] = (idx < N) ? deg[idx] : 0; s += v[i]; }
    sh[t] = s; __syncthreads();
    for (int o = 1; o < 256; o <<= 1) {
        int u = (t >= o) ? sh[t - o] : 0;
        __syncthreads();
        sh[t] += u;
        __syncthreads();
    }
    int run = sh[t] - s + toff[b];
    #pragma unroll
    for (int i = 0; i < 8; i++) {
        int idx = base + i;
        if (idx < N) { rowptr[idx] = run; cmbi[(size_t)idx*8 + 4] = run; run += v[i]; }
    }
}

// ---------------- layer1 node projection: 8 nodes/wave, W1 fragment loaded once per 8 nodes ----------------
__global__ __launch_bounds__(256) void k_proj1(const float* __restrict__ x, const float* __restrict__ W1,
        const float* __restrict__ as1, const float* __restrict__ ad1,
        __half* __restrict__ xs1h, float* __restrict__ as1v, float* __restrict__ cmbf, int N) {
    __shared__ float xr[32][128];                 // 16 KB: 32 node rows
    int tid = threadIdx.x;
    int wave = tid >> 6, lane = tid & 63;
    int nbase = blockIdx.x * 32;
    if (nbase + 32 <= N) {
        const float4* x4 = reinterpret_cast<const float4*>(x + (size_t)nbase * 128);
        #pragma unroll
        for (int i = 0; i < 4; i++) {
            int idx = tid + i * 256;
            reinterpret_cast<float4*>(&xr[0][0])[idx] = x4[idx];
        }
    } else {
        for (int i = 0; i < 16; i++) {
            int flat = tid + i * 256;
            int row = flat >> 7, col = flat & 127;
            int n = nbase + row; if (n >= N) n = N - 1;
            xr[row][col] = x[(size_t)n * 128 + col];
        }
    }
    __syncthreads();
    int cc = lane & 15, kk = lane >> 4;
    int nw = wave * 8;
    const float4* W4 = reinterpret_cast<const float4*>(W1);
    float4 acc[8];
    #pragma unroll
    for (int m = 0; m < 8; m++) acc[m] = make_float4(0.f, 0.f, 0.f, 0.f);
    #pragma unroll 4
    for (int k = kk; k < 128; k += 4) {
        float4 wv = W4[k * 16 + cc];
        #pragma unroll
        for (int m = 0; m < 8; m++) {
            float xv = xr[nw + m][k];
            acc[m].x = fmaf(xv, wv.x, acc[m].x);
            acc[m].y = fmaf(xv, wv.y, acc[m].y);
            acc[m].z = fmaf(xv, wv.z, acc[m].z);
            acc[m].w = fmaf(xv, wv.w, acc[m].w);
        }
    }
    float a_s0 = as1[4*cc], a_s1 = as1[4*cc+1], a_s2 = as1[4*cc+2], a_s3 = as1[4*cc+3];
    float a_d0 = ad1[4*cc], a_d1 = ad1[4*cc+1], a_d2 = ad1[4*cc+2], a_d3 = ad1[4*cc+3];
    #pragma unroll
    for (int m = 0; m < 8; m++) {
        float4 a = acc[m];
        a.x += __shfl_xor(a.x, 16, 64); a.y += __shfl_xor(a.y, 16, 64);
        a.z += __shfl_xor(a.z, 16, 64); a.w += __shfl_xor(a.w, 16, 64);
        a.x += __shfl_xor(a.x, 32, 64); a.y += __shfl_xor(a.y, 32, 64);
        a.z += __shfl_xor(a.z, 32, 64); a.w += __shfl_xor(a.w, 32, 64);
        float ps = a.x*a_s0 + a.y*a_s1 + a.z*a_s2 + a.w*a_s3;
        float pd = a.x*a_d0 + a.y*a_d1 + a.z*a_d2 + a.w*a_d3;
        ps += __shfl_xor(ps, 1, 64); ps += __shfl_xor(ps, 2, 64);
        pd += __shfl_xor(pd, 1, 64); pd += __shfl_xor(pd, 2, 64);
        if (kk == 0) {
            int n = nbase + nw + m; if (n >= N) n = N - 1;
            __half2 h01 = __halves2half2(__float2half_rn(a.x), __float2half_rn(a.y));
            __half2 h23 = __halves2half2(__float2half_rn(a.z), __float2half_rn(a.w));
            uint2 st;
            st.x = *reinterpret_cast<unsigned*>(&h01);
            st.y = *reinterpret_cast<unsigned*>(&h23);
            *reinterpret_cast<uint2*>(&xs1h[(size_t)n*64 + 4*cc]) = st;
            if ((cc & 3) == 0) {
                int h = cc >> 2;
                as1v[n*4 + h] = ps;
                cmbf[(size_t)n*8 + h] = pd;       // ad1v lives in the packed per-dst record
            }
        }
    }
}

// ---------------- edge MLP + weights; direct 16B scatter to CSR slot (no atomics here) ----------------
__global__ __launch_bounds__(256) void k_payload(const float* __restrict__ ef,
                       const float* __restrict__ Em1, const float* __restrict__ eb1,
                       const float* __restrict__ Em2, const float* __restrict__ eb2,
                       const float* __restrict__ cw,
                       const int* __restrict__ src, const int* __restrict__ dst,
                       const int* __restrict__ pw,
                       const float4* __restrict__ as1v4,
                       const float* __restrict__ cmbf, const int* __restrict__ cmbi,
                       uint4* __restrict__ csr_pk, int E) {
    int base = (blockIdx.x * blockDim.x + threadIdx.x) * 4;
    if (base >= E) return;
    int cnt = min(4, E - base);

    float f[4][3]; int sv[4], dv[4], pv[4];
    if (cnt == 4) {
        const float4* ef4 = reinterpret_cast<const float4*>(ef);
        float4 a = ef4[base*3/4 + 0], b = ef4[base*3/4 + 1], c = ef4[base*3/4 + 2];
        f[0][0]=a.x; f[0][1]=a.y; f[0][2]=a.z;
        f[1][0]=a.w; f[1][1]=b.x; f[1][2]=b.y;
        f[2][0]=b.z; f[2][1]=b.w; f[2][2]=c.x;
        f[3][0]=c.y; f[3][1]=c.z; f[3][2]=c.w;
        int4 s4 = *reinterpret_cast<const int4*>(&src[base]);
        int4 d4 = *reinterpret_cast<const int4*>(&dst[base]);
        int4 p4 = *reinterpret_cast<const int4*>(&pw[base]);
        sv[0]=s4.x; sv[1]=s4.y; sv[2]=s4.z; sv[3]=s4.w;
        dv[0]=d4.x; dv[1]=d4.y; dv[2]=d4.z; dv[3]=d4.w;
        pv[0]=p4.x; pv[1]=p4.y; pv[2]=p4.z; pv[3]=p4.w;
    } else {
        for (int i = 0; i < cnt; i++) {
            f[i][0]=ef[(base+i)*3+0]; f[i][1]=ef[(base+i)*3+1]; f[i][2]=ef[(base+i)*3+2];
            sv[i]=src[base+i]; dv[i]=dst[base+i]; pv[i]=pw[base+i];
        }
    }

    #pragma unroll
    for (int i = 0; i < 4; i++) {
        if (i >= cnt) break;
        float f0=f[i][0], f1=f[i][1], f2=f[i][2];
        float t0 = fmaxf(f0*Em1[0]+f1*Em1[3]+f2*Em1[6]+eb1[0], 0.f);
        float t1 = fmaxf(f0*Em1[1]+f1*Em1[4]+f2*Em1[7]+eb1[1], 0.f);
        float t2 = fmaxf(f0*Em1[2]+f1*Em1[5]+f2*Em1[8]+eb1[2], 0.f);
        float u0 = t0*Em2[0]+t1*Em2[3]+t2*Em2[6]+eb2[0];
        float u1 = t0*Em2[1]+t1*Em2[4]+t2*Em2[7]+eb2[1];
        float u2 = t0*Em2[2]+t1*Em2[5]+t2*Em2[8]+eb2[2];
        int s = sv[i], d = dv[i];
        float4 av = as1v4[s];
        float4 bv = *reinterpret_cast<const float4*>(&cmbf[(size_t)d*8]);   // ad1v
        int rp = cmbi[(size_t)d*8 + 4];                                      // rowptr[d], same line
        float w0 = __expf(leaky(av.x + bv.x + u0*cw[0] + u1*cw[4] + u2*cw[8]));
        float w1 = __expf(leaky(av.y + bv.y + u0*cw[1] + u1*cw[5] + u2*cw[9]));
        float w2 = __expf(leaky(av.z + bv.z + u0*cw[2] + u1*cw[6] + u2*cw[10]));
        float w3 = __expf(leaky(av.w + bv.w + u0*cw[3] + u1*cw[7] + u2*cw[11]));
        float e2 = u0*cw[12] + u1*cw[13] + u2*cw[14];
        __half2 lo = __halves2half2(__float2half_rn(w0), __float2half_rn(w1));
        __half2 hi = __halves2half2(__float2half_rn(w2), __float2half_rn(w3));
        uint4 pki;
        pki.x = (unsigned)s;
        pki.y = *reinterpret_cast<unsigned*>(&lo);
        pki.z = *reinterpret_cast<unsigned*>(&hi);
        pki.w = *reinterpret_cast<unsigned*>(&e2);
        csr_pk[rp + pv[i]] = pki;         // position known; fire-and-forget 16B scatter
    }
}

// ---------------- fused layer1: batched-MLP gather loop + ELU + proj2 epilogue ----------------
__global__ __launch_bounds__(256, 4) void k_gat1(
        const int* __restrict__ rowptr, const uint4* __restrict__ csr_pk,
        const __half* __restrict__ xs1h,
        const float* __restrict__ b1, const float* __restrict__ W2,
        const float* __restrict__ as2, const float* __restrict__ ad2,
        float2* __restrict__ pk2, float* __restrict__ ad2v, int N) {
    int wave = threadIdx.x >> 6, lane = threadIdx.x & 63;
    int d = blockIdx.x * 4 + wave;
    if (d >= N) return;
    int beg = rowptr[d], end = rowptr[d+1];
    int jj = lane >> 2, hh = lane & 3;
    int k = lane, hk = lane >> 4;
    const __half* xcol = xs1h + k;                // column view: row s at xcol[s*64]
    float smacc = 0.f, acc = 0.f;
    for (int off = beg; off < end; off += 16) {
        int j = off + jj;
        float w = 0.f; int s = 0;
        if (j < end) {
            uint4 p = csr_pk[j];
            s = (int)p.x;
            unsigned wb = (hh < 2) ? p.y : p.z;
            __half2 h2 = *reinterpret_cast<__half2*>(&wb);
            w = (hh & 1) ? __high2float(h2) : __low2float(h2);
        }
        smacc += w;
        if (end - off >= 16) {
            // phase 1: src-index shuffles (independent)
            int st[16];
            #pragma unroll
            for (int t = 0; t < 16; ++t) st[t] = __shfl(s, t*4, 64);
            // phase 2: issue ALL 16 gathers -> 16 loads in flight
            __half hv[16];
            #pragma unroll
            for (int t = 0; t < 16; ++t) hv[t] = xcol[(size_t)st[t] << 6];
            // phase 3: weight shuffles overlap the load latency
            float wt[16];
            #pragma unroll
            for (int t = 0; t < 16; ++t) wt[t] = __shfl(w, t*4 + hk, 64);
            // phase 4: consume
            #pragma unroll
            for (int t = 0; t < 16; ++t) acc = fmaf(wt[t], __half2float(hv[t]), acc);
        } else {
            int lim = end - off;
            for (int t = 0; t < lim; ++t) {
                float wt = __shfl(w, t*4 + hk, 64);
                int stx  = __shfl(s, t*4, 64);
                acc = fmaf(wt, __half2float(xcol[(size_t)stx << 6]), acc);
            }
        }
    }
    smacc += __shfl_xor(smacc, 4, 64);
    smacc += __shfl_xor(smacc, 8, 64);
    smacc += __shfl_xor(smacc, 16, 64);
    smacc += __shfl_xor(smacc, 32, 64);
    float sm = __shfl(smacc, hk, 64);
    float h = acc / (sm + 1e-16f);
    float v = h + b1[k];
    v = v > 0.f ? v : expm1f(v);
    float p0 = v * W2[k*2 + 0], p1 = v * W2[k*2 + 1];
    #pragma unroll
    for (int o = 32; o >= 1; o >>= 1) { p0 += __shfl_xor(p0,o,64); p1 += __shfl_xor(p1,o,64); }
    if (lane == 0) {
        float2 q;
        q.x = p0*as2[0] + p1*as2[1];
        __half2 xv = __halves2half2(__float2half_rn(p0), __float2half_rn(p1));
        q.y = *reinterpret_cast<float*>(&xv);
        pk2[d] = q;
        ad2v[d] = p0*ad2[0] + p1*ad2[1];
    }
}

// ---------------- fused layer2: single pass, 16 lanes per node (sequential payload reads) ----------------
__global__ __launch_bounds__(256) void k_gat2(
        const int* __restrict__ rowptr, const uint4* __restrict__ csr_pk,
        const float2* __restrict__ pk2, const float* __restrict__ ad2v,
        const float* __restrict__ b2, float* __restrict__ out, int N) {
    int t = blockIdx.x * blockDim.x + threadIdx.x;
    int d = t >> 4, j16 = t & 15;
    if (d >= N) return;
    int beg = rowptr[d], end = rowptr[d+1];
    float add = ad2v[d];
    float sm = 0.f, p0 = 0.f, p1 = 0.f;
    for (int off = beg; off < end; off += 16) {
        int j = off + j16;
        if (j < end) {
            uint4 p = csr_pk[j];
            int s = (int)p.x;
            float ea2 = *reinterpret_cast<float*>(&p.w);
            float2 q = pk2[s];
            float w = __expf(leaky(q.x + add + ea2));
            __half2 xv = *reinterpret_cast<__half2*>(&q.y);
            p0 = fmaf(w, __low2float(xv), p0);
            p1 = fmaf(w, __high2float(xv), p1);
            sm += w;
        }
    }
    #pragma unroll
    for (int o = 1; o < 16; o <<= 1) {
        sm += __shfl_xor(sm, o, 16);
        p0 += __shfl_xor(p0, o, 16);
        p1 += __shfl_xor(p1, o, 16);
    }
    if (j16 == 0) {
        float inv = 1.f / (sm + 1e-16f);
        out[d*2+0] = p0*inv + b2[0];
        out[d*2+1] = p1*inv + b2[1];
    }
}

extern "C" void kernel_launch(void* const* d_in, const int* in_sizes, int n_in,
                              void* d_out, int out_size, void* d_ws, size_t ws_size,
                              hipStream_t stream) {
    const float* x   = (const float*)d_in[0];
    const int*   ei  = (const int*)d_in[1];
    const float* ef  = (const float*)d_in[2];
    const float* Em1 = (const float*)d_in[3];
    const float* eb1 = (const float*)d_in[4];
    const float* Em2 = (const float*)d_in[5];
    const float* eb2 = (const float*)d_in[6];
    const float* W1  = (const float*)d_in[7];
    const float* as1 = (const float*)d_in[8];
    const float* ad1 = (const float*)d_in[9];
    const float* We1 = (const float*)d_in[10];
    const float* ae1 = (const float*)d_in[11];
    const float* b1  = (const float*)d_in[12];
    const float* W2  = (const float*)d_in[13];
    const float* as2 = (const float*)d_in[14];
    const float* ad2 = (const float*)d_in[15];
    const float* We2 = (const float*)d_in[16];
    const float* ae2 = (const float*)d_in[17];
    const float* b2  = (const float*)d_in[18];

    const int N = in_sizes[0] / 128;
    const int E = in_sizes[1] / 2;
    const int* srcp = ei;
    const int* dstp = ei + E;

    uintptr_t w = (uintptr_t)d_ws;
    auto alloc = [&](size_t bytes) -> void* {
        uintptr_t p = w; w += (bytes + 255) & ~(size_t)255; return (void*)p;
    };
    const int nb = (N + SCAN_TILE - 1) / SCAN_TILE;
    int*    deg     = (int*)alloc((size_t)N * sizeof(int));
    int*    rowptr  = (int*)alloc(((size_t)N + 1) * sizeof(int));
    int*    tsum    = (int*)alloc((size_t)nb * sizeof(int));
    int*    toff    = (int*)alloc((size_t)(nb + 1) * sizeof(int));
    float*  cw      = (float*)alloc(16 * sizeof(float));
    int*    pw      = (int*)alloc((size_t)E * sizeof(int));
    uint4*  csr_pk  = (uint4*)alloc((size_t)E * sizeof(uint4));
    __half* xs1h    = (__half*)alloc((size_t)N * 64 * sizeof(__half));
    float*  as1v    = (float*)alloc((size_t)N * 4 * sizeof(float));
    float*  cmb     = (float*)alloc((size_t)N * 8 * sizeof(float));   // {ad1v float4, rowptr int, pad}
    float2* pk2     = (float2*)alloc((size_t)N * sizeof(float2));
    float*  ad2v    = (float*)alloc((size_t)N * sizeof(float));

    const int B = 256;

    hipMemsetAsync(deg, 0, (size_t)N * sizeof(int), stream);
    k_pw<<<(E/4+B-1)/B + 1, B, 0, stream>>>(dstp, deg, pw, E, We1, ae1, We2, ae2, cw);
    k_scan_partial<<<nb, 256, 0, stream>>>(deg, tsum, N);
    k_scan_tsum<<<1, 64, 0, stream>>>(tsum, toff, rowptr, nb, N);
    k_scan_final<<<nb, 256, 0, stream>>>(deg, toff, rowptr, (int*)cmb, N);
    k_proj1<<<(N+31)/32, 256, 0, stream>>>(x, W1, as1, ad1, xs1h, as1v, cmb, N);
    k_payload<<<(E/4+B-1)/B + 1, B, 0, stream>>>(ef, Em1, eb1, Em2, eb2, cw,
                                                 srcp, dstp, pw, (const float4*)as1v,
                                                 cmb, (const int*)cmb, csr_pk, E);
    k_gat1<<<(N+3)/4, 256, 0, stream>>>(rowptr, csr_pk, xs1h, b1, W2, as2, ad2, pk2, ad2v, N);
    k_gat2<<<(N*16+B-1)/B, B, 0, stream>>>(rowptr, csr_pk, pk2, ad2v, b2, (float*)d_out, N);
}

// Round 11
// 251.514 us; speedup vs baseline: 1.3139x; 1.0918x over previous
//
#include <hip/hip_runtime.h>
#include <hip/hip_fp16.h>
#include <math.h>
#include <stdint.h>

#define NEG_SLOPE 0.2f
#define SCAN_TILE 2048

__device__ __forceinline__ float leaky(float a) { return a > 0.f ? a : NEG_SLOPE * a; }
__device__ __forceinline__ __half2 u2h2(unsigned u) { return *reinterpret_cast<__half2*>(&u); }

// ---------------- pass 1: degree histogram + within-node position (single atomic pass) ----------------
__global__ __launch_bounds__(256) void k_pw(const int* __restrict__ dst, int* __restrict__ deg,
                                            int* __restrict__ pw, int E,
                                            const float* __restrict__ We1, const float* __restrict__ ae1,
                                            const float* __restrict__ We2, const float* __restrict__ ae2,
                                            float* __restrict__ cw) {
    if (blockIdx.x == 0 && threadIdx.x == 0) {
        for (int i = 0; i < 3; i++)
            for (int h = 0; h < 4; h++) {
                float s = 0.f;
                for (int m = 0; m < 16; m++) s += We1[i*64 + h*16 + m] * ae1[h*16 + m];
                cw[i*4 + h] = s;
            }
        for (int i = 0; i < 3; i++) cw[12 + i] = We2[i*2]*ae2[0] + We2[i*2+1]*ae2[1];
    }
    int base = (blockIdx.x * blockDim.x + threadIdx.x) * 4;
    if (base >= E) return;
    if (base + 3 < E) {
        int4 dv = *reinterpret_cast<const int4*>(&dst[base]);
        int4 pv;
        pv.x = atomicAdd(&deg[dv.x], 1);
        pv.y = atomicAdd(&deg[dv.y], 1);
        pv.z = atomicAdd(&deg[dv.z], 1);
        pv.w = atomicAdd(&deg[dv.w], 1);
        *reinterpret_cast<int4*>(&pw[base]) = pv;
    } else {
        for (int i = base; i < E; i++) pw[i] = atomicAdd(&deg[dst[i]], 1);
    }
}

__global__ __launch_bounds__(256) void k_scan_partial(const int* __restrict__ deg, int* __restrict__ tsum, int N) {
    __shared__ int sh[256];
    int b = blockIdx.x, t = threadIdx.x;
    int base = b * SCAN_TILE + t * 8;
    int s = 0;
    #pragma unroll
    for (int i = 0; i < 8; i++) { int idx = base + i; s += (idx < N) ? deg[idx] : 0; }
    sh[t] = s; __syncthreads();
    for (int o = 128; o > 0; o >>= 1) { if (t < o) sh[t] += sh[t + o]; __syncthreads(); }
    if (t == 0) tsum[b] = sh[0];
}

__global__ void k_scan_tsum(const int* __restrict__ tsum, int* __restrict__ toff,
                            int* __restrict__ rowptr, int nb, int N) {
    if (threadIdx.x == 0 && blockIdx.x == 0) {
        int run = 0;
        for (int i = 0; i < nb; i++) { toff[i] = run; run += tsum[i]; }
        rowptr[N] = run;
    }
}

__global__ __launch_bounds__(256) void k_scan_final(const int* __restrict__ deg, const int* __restrict__ toff,
        int* __restrict__ rowptr, int* __restrict__ cmbi, int N) {
    __shared__ int sh[256];
    int b = blockIdx.x, t = threadIdx.x;
    int base = b * SCAN_TILE + t * 8;
    int v[8]; int s = 0;
    #pragma unroll
    for (int i = 0; i < 8; i++) { int idx = base + i; v[i] = (idx < N) ? deg[idx] : 0; s += v[i]; }
    sh[t] = s; __syncthreads();
    for (int o = 1; o < 256; o <<= 1) {
        int u = (t >= o) ? sh[t - o] : 0;
        __syncthreads();
        sh[t] += u;
        __syncthreads();
    }
    int run = sh[t] - s + toff[b];
    #pragma unroll
    for (int i = 0; i < 8; i++) {
        int idx = base + i;
        if (idx < N) { rowptr[idx] = run; cmbi[(size_t)idx*8 + 4] = run; run += v[i]; }
    }
}

// ---------------- layer1 node projection: 8 nodes/wave, W1 fragment loaded once per 8 nodes ----------------
__global__ __launch_bounds__(256) void k_proj1(const float* __restrict__ x, const float* __restrict__ W1,
        const float* __restrict__ as1, const float* __restrict__ ad1,
        __half* __restrict__ xs1h, float* __restrict__ as1v, float* __restrict__ cmbf, int N) {
    __shared__ float xr[32][128];                 // 16 KB: 32 node rows
    int tid = threadIdx.x;
    int wave = tid >> 6, lane = tid & 63;
    int nbase = blockIdx.x * 32;
    if (nbase + 32 <= N) {
        const float4* x4 = reinterpret_cast<const float4*>(x + (size_t)nbase * 128);
        #pragma unroll
        for (int i = 0; i < 4; i++) {
            int idx = tid + i * 256;
            reinterpret_cast<float4*>(&xr[0][0])[idx] = x4[idx];
        }
    } else {
        for (int i = 0; i < 16; i++) {
            int flat = tid + i * 256;
            int row = flat >> 7, col = flat & 127;
            int n = nbase + row; if (n >= N) n = N - 1;
            xr[row][col] = x[(size_t)n * 128 + col];
        }
    }
    __syncthreads();
    int cc = lane & 15, kk = lane >> 4;
    int nw = wave * 8;
    const float4* W4 = reinterpret_cast<const float4*>(W1);
    float4 acc[8];
    #pragma unroll
    for (int m = 0; m < 8; m++) acc[m] = make_float4(0.f, 0.f, 0.f, 0.f);
    #pragma unroll 4
    for (int k = kk; k < 128; k += 4) {
        float4 wv = W4[k * 16 + cc];
        #pragma unroll
        for (int m = 0; m < 8; m++) {
            float xv = xr[nw + m][k];
            acc[m].x = fmaf(xv, wv.x, acc[m].x);
            acc[m].y = fmaf(xv, wv.y, acc[m].y);
            acc[m].z = fmaf(xv, wv.z, acc[m].z);
            acc[m].w = fmaf(xv, wv.w, acc[m].w);
        }
    }
    float a_s0 = as1[4*cc], a_s1 = as1[4*cc+1], a_s2 = as1[4*cc+2], a_s3 = as1[4*cc+3];
    float a_d0 = ad1[4*cc], a_d1 = ad1[4*cc+1], a_d2 = ad1[4*cc+2], a_d3 = ad1[4*cc+3];
    #pragma unroll
    for (int m = 0; m < 8; m++) {
        float4 a = acc[m];
        a.x += __shfl_xor(a.x, 16, 64); a.y += __shfl_xor(a.y, 16, 64);
        a.z += __shfl_xor(a.z, 16, 64); a.w += __shfl_xor(a.w, 16, 64);
        a.x += __shfl_xor(a.x, 32, 64); a.y += __shfl_xor(a.y, 32, 64);
        a.z += __shfl_xor(a.z, 32, 64); a.w += __shfl_xor(a.w, 32, 64);
        float ps = a.x*a_s0 + a.y*a_s1 + a.z*a_s2 + a.w*a_s3;
        float pd = a.x*a_d0 + a.y*a_d1 + a.z*a_d2 + a.w*a_d3;
        ps += __shfl_xor(ps, 1, 64); ps += __shfl_xor(ps, 2, 64);
        pd += __shfl_xor(pd, 1, 64); pd += __shfl_xor(pd, 2, 64);
        if (kk == 0) {
            int n = nbase + nw + m; if (n >= N) n = N - 1;
            __half2 h01 = __halves2half2(__float2half_rn(a.x), __float2half_rn(a.y));
            __half2 h23 = __halves2half2(__float2half_rn(a.z), __float2half_rn(a.w));
            uint2 st;
            st.x = *reinterpret_cast<unsigned*>(&h01);
            st.y = *reinterpret_cast<unsigned*>(&h23);
            *reinterpret_cast<uint2*>(&xs1h[(size_t)n*64 + 4*cc]) = st;
            if ((cc & 3) == 0) {
                int h = cc >> 2;
                as1v[n*4 + h] = ps;
                cmbf[(size_t)n*8 + h] = pd;
            }
        }
    }
}

// ---------------- edge MLP + weights; direct 16B scatter to CSR slot (no atomics here) ----------------
__global__ __launch_bounds__(256) void k_payload(const float* __restrict__ ef,
                       const float* __restrict__ Em1, const float* __restrict__ eb1,
                       const float* __restrict__ Em2, const float* __restrict__ eb2,
                       const float* __restrict__ cw,
                       const int* __restrict__ src, const int* __restrict__ dst,
                       const int* __restrict__ pw,
                       const float4* __restrict__ as1v4,
                       const float* __restrict__ cmbf, const int* __restrict__ cmbi,
                       uint4* __restrict__ csr_pk, int E) {
    int base = (blockIdx.x * blockDim.x + threadIdx.x) * 4;
    if (base >= E) return;
    int cnt = min(4, E - base);

    float f[4][3]; int sv[4], dv[4], pv[4];
    if (cnt == 4) {
        const float4* ef4 = reinterpret_cast<const float4*>(ef);
        float4 a = ef4[base*3/4 + 0], b = ef4[base*3/4 + 1], c = ef4[base*3/4 + 2];
        f[0][0]=a.x; f[0][1]=a.y; f[0][2]=a.z;
        f[1][0]=a.w; f[1][1]=b.x; f[1][2]=b.y;
        f[2][0]=b.z; f[2][1]=b.w; f[2][2]=c.x;
        f[3][0]=c.y; f[3][1]=c.z; f[3][2]=c.w;
        int4 s4 = *reinterpret_cast<const int4*>(&src[base]);
        int4 d4 = *reinterpret_cast<const int4*>(&dst[base]);
        int4 p4 = *reinterpret_cast<const int4*>(&pw[base]);
        sv[0]=s4.x; sv[1]=s4.y; sv[2]=s4.z; sv[3]=s4.w;
        dv[0]=d4.x; dv[1]=d4.y; dv[2]=d4.z; dv[3]=d4.w;
        pv[0]=p4.x; pv[1]=p4.y; pv[2]=p4.z; pv[3]=p4.w;
    } else {
        for (int i = 0; i < cnt; i++) {
            f[i][0]=ef[(base+i)*3+0]; f[i][1]=ef[(base+i)*3+1]; f[i][2]=ef[(base+i)*3+2];
            sv[i]=src[base+i]; dv[i]=dst[base+i]; pv[i]=pw[base+i];
        }
    }

    #pragma unroll
    for (int i = 0; i < 4; i++) {
        if (i >= cnt) break;
        float f0=f[i][0], f1=f[i][1], f2=f[i][2];
        float t0 = fmaxf(f0*Em1[0]+f1*Em1[3]+f2*Em1[6]+eb1[0], 0.f);
        float t1 = fmaxf(f0*Em1[1]+f1*Em1[4]+f2*Em1[7]+eb1[1], 0.f);
        float t2 = fmaxf(f0*Em1[2]+f1*Em1[5]+f2*Em1[8]+eb1[2], 0.f);
        float u0 = t0*Em2[0]+t1*Em2[3]+t2*Em2[6]+eb2[0];
        float u1 = t0*Em2[1]+t1*Em2[4]+t2*Em2[7]+eb2[1];
        float u2 = t0*Em2[2]+t1*Em2[5]+t2*Em2[8]+eb2[2];
        int s = sv[i], d = dv[i];
        float4 av = as1v4[s];
        float4 bv = *reinterpret_cast<const float4*>(&cmbf[(size_t)d*8]);
        int rp = cmbi[(size_t)d*8 + 4];
        float w0 = __expf(leaky(av.x + bv.x + u0*cw[0] + u1*cw[4] + u2*cw[8]));
        float w1 = __expf(leaky(av.y + bv.y + u0*cw[1] + u1*cw[5] + u2*cw[9]));
        float w2 = __expf(leaky(av.z + bv.z + u0*cw[2] + u1*cw[6] + u2*cw[10]));
        float w3 = __expf(leaky(av.w + bv.w + u0*cw[3] + u1*cw[7] + u2*cw[11]));
        float e2 = u0*cw[12] + u1*cw[13] + u2*cw[14];
        __half2 lo = __halves2half2(__float2half_rn(w0), __float2half_rn(w1));
        __half2 hi = __halves2half2(__float2half_rn(w2), __float2half_rn(w3));
        uint4 pki;
        pki.x = (unsigned)s;
        pki.y = *reinterpret_cast<unsigned*>(&lo);
        pki.z = *reinterpret_cast<unsigned*>(&hi);
        pki.w = *reinterpret_cast<unsigned*>(&e2);
        csr_pk[rp + pv[i]] = pki;
    }
}

// ---------------- fused layer1: lane=(edge-slot,channel-quad); 4 wide gathers in flight ----------------
__global__ __launch_bounds__(256, 4) void k_gat1(
        const int* __restrict__ rowptr, const uint4* __restrict__ csr_pk,
        const __half* __restrict__ xs1h,
        const float* __restrict__ b1, const float* __restrict__ W2,
        const float* __restrict__ as2, const float* __restrict__ ad2,
        float2* __restrict__ pk2, float* __restrict__ ad2v, int N) {
    int wave = threadIdx.x >> 6, lane = threadIdx.x & 63;
    int d = blockIdx.x * 4 + wave;
    if (d >= N) return;
    int beg = rowptr[d], end = rowptr[d+1];
    int cg = lane & 15, e4 = lane >> 4;           // channel quad 4cg..4cg+3 ; edge slot
    int hh = cg >> 2;                             // my head
    const __half* xbase = xs1h + 4 * cg;
    float4 acc = make_float4(0.f, 0.f, 0.f, 0.f); // channel accumulators
    float4 wv  = make_float4(0.f, 0.f, 0.f, 0.f); // per-head weight sums (this lane's record edges)
    for (int off = beg; off < end; off += 16) {
        int j = off + cg;                         // record for edge (off+cg)
        uint4 p = make_uint4(0u, 0u, 0u, 0u);
        if (j < end) p = csr_pk[j];
        int si = (int)p.x;
        __half2 wl = u2h2(p.y), whp = u2h2(p.z);
        wv.x += __low2float(wl);  wv.y += __high2float(wl);
        wv.z += __low2float(whp); wv.w += __high2float(whp);
        // phase 1: distribute src idx + BOTH weight words; select with LOCAL head after shuffle
        int st0, st1, st2, st3; float wt0, wt1, wt2, wt3;
        {
            int sl0 = 0*4 + e4, sl1 = 1*4 + e4, sl2 = 2*4 + e4, sl3 = 3*4 + e4;
            st0 = __shfl(si, sl0, 16); st1 = __shfl(si, sl1, 16);
            st2 = __shfl(si, sl2, 16); st3 = __shfl(si, sl3, 16);
            unsigned y0 = __shfl(p.y, sl0, 16), z0 = __shfl(p.z, sl0, 16);
            unsigned y1 = __shfl(p.y, sl1, 16), z1 = __shfl(p.z, sl1, 16);
            unsigned y2 = __shfl(p.y, sl2, 16), z2 = __shfl(p.z, sl2, 16);
            unsigned y3 = __shfl(p.y, sl3, 16), z3 = __shfl(p.z, sl3, 16);
            unsigned q0 = (hh < 2) ? y0 : z0;
            unsigned q1 = (hh < 2) ? y1 : z1;
            unsigned q2 = (hh < 2) ? y2 : z2;
            unsigned q3 = (hh < 2) ? y3 : z3;
            wt0 = (hh & 1) ? __high2float(u2h2(q0)) : __low2float(u2h2(q0));
            wt1 = (hh & 1) ? __high2float(u2h2(q1)) : __low2float(u2h2(q1));
            wt2 = (hh & 1) ? __high2float(u2h2(q2)) : __low2float(u2h2(q2));
            wt3 = (hh & 1) ? __high2float(u2h2(q3)) : __low2float(u2h2(q3));
        }
        // phase 2: issue all 4 row-quad gathers (8B each; 4 edges x 128B per wave instr)
        uint2 g0 = *reinterpret_cast<const uint2*>(xbase + ((size_t)st0 << 6));
        uint2 g1 = *reinterpret_cast<const uint2*>(xbase + ((size_t)st1 << 6));
        uint2 g2 = *reinterpret_cast<const uint2*>(xbase + ((size_t)st2 << 6));
        uint2 g3 = *reinterpret_cast<const uint2*>(xbase + ((size_t)st3 << 6));
        // phase 3: consume
        __half2 a, b;
        a = u2h2(g0.x); b = u2h2(g0.y);
        acc.x = fmaf(wt0, __low2float(a), acc.x); acc.y = fmaf(wt0, __high2float(a), acc.y);
        acc.z = fmaf(wt0, __low2float(b), acc.z); acc.w = fmaf(wt0, __high2float(b), acc.w);
        a = u2h2(g1.x); b = u2h2(g1.y);
        acc.x = fmaf(wt1, __low2float(a), acc.x); acc.y = fmaf(wt1, __high2float(a), acc.y);
        acc.z = fmaf(wt1, __low2float(b), acc.z); acc.w = fmaf(wt1, __high2float(b), acc.w);
        a = u2h2(g2.x); b = u2h2(g2.y);
        acc.x = fmaf(wt2, __low2float(a), acc.x); acc.y = fmaf(wt2, __high2float(a), acc.y);
        acc.z = fmaf(wt2, __low2float(b), acc.z); acc.w = fmaf(wt2, __high2float(b), acc.w);
        a = u2h2(g3.x); b = u2h2(g3.y);
        acc.x = fmaf(wt3, __low2float(a), acc.x); acc.y = fmaf(wt3, __high2float(a), acc.y);
        acc.z = fmaf(wt3, __low2float(b), acc.z); acc.w = fmaf(wt3, __high2float(b), acc.w);
    }
    // reduce channel accumulators across the 4 edge-slot segments (lane bits 4,5)
    acc.x += __shfl_xor(acc.x, 16, 64); acc.y += __shfl_xor(acc.y, 16, 64);
    acc.z += __shfl_xor(acc.z, 16, 64); acc.w += __shfl_xor(acc.w, 16, 64);
    acc.x += __shfl_xor(acc.x, 32, 64); acc.y += __shfl_xor(acc.y, 32, 64);
    acc.z += __shfl_xor(acc.z, 32, 64); acc.w += __shfl_xor(acc.w, 32, 64);
    // reduce per-head weight sums within the 16-lane group (covers all edges)
    #pragma unroll
    for (int o = 1; o <= 8; o <<= 1) {
        wv.x += __shfl_xor(wv.x, o, 16); wv.y += __shfl_xor(wv.y, o, 16);
        wv.z += __shfl_xor(wv.z, o, 16); wv.w += __shfl_xor(wv.w, o, 16);
    }
    float sm = (hh == 0) ? wv.x : (hh == 1) ? wv.y : (hh == 2) ? wv.z : wv.w;
    float inv = 1.f / (sm + 1e-16f);
    // epilogue: bias + ELU + layer2 projection; channels 4cg..4cg+3 in this lane
    float v0 = acc.x * inv + b1[4*cg + 0];
    float v1 = acc.y * inv + b1[4*cg + 1];
    float v2 = acc.z * inv + b1[4*cg + 2];
    float v3 = acc.w * inv + b1[4*cg + 3];
    v0 = v0 > 0.f ? v0 : expm1f(v0);
    v1 = v1 > 0.f ? v1 : expm1f(v1);
    v2 = v2 > 0.f ? v2 : expm1f(v2);
    v3 = v3 > 0.f ? v3 : expm1f(v3);
    float p0 = v0*W2[(4*cg+0)*2] + v1*W2[(4*cg+1)*2] + v2*W2[(4*cg+2)*2] + v3*W2[(4*cg+3)*2];
    float p1 = v0*W2[(4*cg+0)*2+1] + v1*W2[(4*cg+1)*2+1] + v2*W2[(4*cg+2)*2+1] + v3*W2[(4*cg+3)*2+1];
    #pragma unroll
    for (int o = 1; o <= 8; o <<= 1) { p0 += __shfl_xor(p0, o, 16); p1 += __shfl_xor(p1, o, 16); }
    if (lane == 0) {
        float2 q;
        q.x = p0*as2[0] + p1*as2[1];
        __half2 xv = __halves2half2(__float2half_rn(p0), __float2half_rn(p1));
        q.y = *reinterpret_cast<float*>(&xv);
        pk2[d] = q;
        ad2v[d] = p0*ad2[0] + p1*ad2[1];
    }
}

// ---------------- fused layer2: single pass, 16 lanes per node (sequential payload reads) ----------------
__global__ __launch_bounds__(256) void k_gat2(
        const int* __restrict__ rowptr, const uint4* __restrict__ csr_pk,
        const float2* __restrict__ pk2, const float* __restrict__ ad2v,
        const float* __restrict__ b2, float* __restrict__ out, int N) {
    int t = blockIdx.x * blockDim.x + threadIdx.x;
    int d = t >> 4, j16 = t & 15;
    if (d >= N) return;
    int beg = rowptr[d], end = rowptr[d+1];
    float add = ad2v[d];
    float sm = 0.f, p0 = 0.f, p1 = 0.f;
    for (int off = beg; off < end; off += 16) {
        int j = off + j16;
        if (j < end) {
            uint4 p = csr_pk[j];
            int s = (int)p.x;
            float ea2 = *reinterpret_cast<float*>(&p.w);
            float2 q = pk2[s];
            float w = __expf(leaky(q.x + add + ea2));
            __half2 xv = *reinterpret_cast<__half2*>(&q.y);
            p0 = fmaf(w, __low2float(xv), p0);
            p1 = fmaf(w, __high2float(xv), p1);
            sm += w;
        }
    }
    #pragma unroll
    for (int o = 1; o < 16; o <<= 1) {
        sm += __shfl_xor(sm, o, 16);
        p0 += __shfl_xor(p0, o, 16);
        p1 += __shfl_xor(p1, o, 16);
    }
    if (j16 == 0) {
        float inv = 1.f / (sm + 1e-16f);
        out[d*2+0] = p0*inv + b2[0];
        out[d*2+1] = p1*inv + b2[1];
    }
}

extern "C" void kernel_launch(void* const* d_in, const int* in_sizes, int n_in,
                              void* d_out, int out_size, void* d_ws, size_t ws_size,
                              hipStream_t stream) {
    const float* x   = (const float*)d_in[0];
    const int*   ei  = (const int*)d_in[1];
    const float* ef  = (const float*)d_in[2];
    const float* Em1 = (const float*)d_in[3];
    const float* eb1 = (const float*)d_in[4];
    const float* Em2 = (const float*)d_in[5];
    const float* eb2 = (const float*)d_in[6];
    const float* W1  = (const float*)d_in[7];
    const float* as1 = (const float*)d_in[8];
    const float* ad1 = (const float*)d_in[9];
    const float* We1 = (const float*)d_in[10];
    const float* ae1 = (const float*)d_in[11];
    const float* b1  = (const float*)d_in[12];
    const float* W2  = (const float*)d_in[13];
    const float* as2 = (const float*)d_in[14];
    const float* ad2 = (const float*)d_in[15];
    const float* We2 = (const float*)d_in[16];
    const float* ae2 = (const float*)d_in[17];
    const float* b2  = (const float*)d_in[18];

    const int N = in_sizes[0] / 128;
    const int E = in_sizes[1] / 2;
    const int* srcp = ei;
    const int* dstp = ei + E;

    uintptr_t w = (uintptr_t)d_ws;
    auto alloc = [&](size_t bytes) -> void* {
        uintptr_t p = w; w += (bytes + 255) & ~(size_t)255; return (void*)p;
    };
    const int nb = (N + SCAN_TILE - 1) / SCAN_TILE;
    int*    deg     = (int*)alloc((size_t)N * sizeof(int));
    int*    rowptr  = (int*)alloc(((size_t)N + 1) * sizeof(int));
    int*    tsum    = (int*)alloc((size_t)nb * sizeof(int));
    int*    toff    = (int*)alloc((size_t)(nb + 1) * sizeof(int));
    float*  cw      = (float*)alloc(16 * sizeof(float));
    int*    pw      = (int*)alloc((size_t)E * sizeof(int));
    uint4*  csr_pk  = (uint4*)alloc((size_t)E * sizeof(uint4));
    __half* xs1h    = (__half*)alloc((size_t)N * 64 * sizeof(__half));
    float*  as1v    = (float*)alloc((size_t)N * 4 * sizeof(float));
    float*  cmb     = (float*)alloc((size_t)N * 8 * sizeof(float));
    float2* pk2     = (float2*)alloc((size_t)N * sizeof(float2));
    float*  ad2v    = (float*)alloc((size_t)N * sizeof(float));

    const int B = 256;

    hipMemsetAsync(deg, 0, (size_t)N * sizeof(int), stream);
    k_pw<<<(E/4+B-1)/B + 1, B, 0, stream>>>(dstp, deg, pw, E, We1, ae1, We2, ae2, cw);
    k_scan_partial<<<nb, 256, 0, stream>>>(deg, tsum, N);
    k_scan_tsum<<<1, 64, 0, stream>>>(tsum, toff, rowptr, nb, N);
    k_scan_final<<<nb, 256, 0, stream>>>(deg, toff, rowptr, (int*)cmb, N);
    k_proj1<<<(N+31)/32, 256, 0, stream>>>(x, W1, as1, ad1, xs1h, as1v, cmb, N);
    k_payload<<<(E/4+B-1)/B + 1, B, 0, stream>>>(ef, Em1, eb1, Em2, eb2, cw,
                                                 srcp, dstp, pw, (const float4*)as1v,
                                                 cmb, (const int*)cmb, csr_pk, E);
    k_gat1<<<(N+3)/4, 256, 0, stream>>>(rowptr, csr_pk, xs1h, b1, W2, as2, ad2, pk2, ad2v, N);
    k_gat2<<<(N*16+B-1)/B, B, 0, stream>>>(rowptr, csr_pk, pk2, ad2v, b2, (float*)d_out, N);
}